// Round 3
// baseline (80.496 us; speedup 1.0000x reference)
//
#include <hip/hip_runtime.h>

// HONU order-3 via MFMA:
//   out[b] = sum_p xb[b,i0(p)]*xb[b,i1(p)] * S[b,p],  S = Xb @ Wexp^T,
//   Wexp[p,k] = w(i0,i1,k) for k in [i1,128], else 0 (banded, ~27% dense).
// comb_idx input ignored (lex order -> analytic weight index).
//
// R13: split the pipeline. rocprof showed the harness's 268MB workspace
// re-poison fill (~40us) is a fixed per-iteration tax; honu_fused itself is
// ~37us and its dominant modeled cost is the B-fragment pack (scattered w
// gather + bf16 pack), duplicated 4x across by-chunks. Now a small expansion
// kernel writes the fragment-ready bf16 Wexp image (2.06MB, layout
// [group][s][q][n][8xbf16]) + per-pair decode table into d_ws once per launch;
// the main kernel DMAs its 16KB B-tile straight into LDS via
// global_load_lds dwordx4 (contiguous global == linear LDS image) and keeps
// only stage-x -> A-frag -> MFMA -> fused fp32 epilogue. Fragment values are
// bit-identical to the R12 passing kernel. ws is re-poisoned by the harness
// every iteration, so expansion runs every launch (self-contained).
//
// R14: identical to R13 — previous round was a GPUAcquisitionTimeout (infra),
// the kernel never ran. Resubmitting for a clean A/B against R12's 79.6us.

#define NF      129
#define NCOMB   366145
#define NPAIR   8385            // pairs i0<=i1
#define NT      4               // 16-pair tiles per block (64 pairs)
#define NCHUNK  132             // 132*64 = 8448 >= NPAIR
#define NKS     4               // k-steps cover k=0..127; k=128 in epilogue
#define NGROUP  (NCHUNK * 4)    // 528 groups of 16 pairs
#define DEC_OFF (4u << 20)      // dec2 table at +4MB inside d_ws

typedef short bf16x8 __attribute__((ext_vector_type(8)));
typedef float f32x4  __attribute__((ext_vector_type(4)));

union i4b8 { int4 i; bf16x8 b; };

static __device__ inline unsigned bfpack2(float lo, float hi) {
    union { float f; unsigned u; } a, b; a.f = lo; b.f = hi;
    return ((b.u + 0x8000u) & 0xffff0000u) | ((a.u + 0x8000u) >> 16);
}

static __device__ inline void dpair(int p, int& i0, int& i1) {
    int t = (int)((259.0f - sqrtf((float)(67081 - 8 * p))) * 0.5f);
    t = t < 0 ? 0 : (t > 128 ? 128 : t);
    while (t < 128 && ((t + 1) * (258 - t)) / 2 <= p) ++t;
    while (t > 0   && (t * (259 - t)) / 2      >  p) --t;
    i0 = t; i1 = t + (p - (t * (259 - t)) / 2);
}

static __device__ inline int mbase(int i0, int i1) {
    const int n0 = NF - i0, n1 = NF - i1;
    return NCOMB - (n0 * (n0 + 1) * (n0 + 2)) / 6
                 + ((n0 * (n0 + 1)) >> 1) - ((n1 * (n1 + 1)) >> 1);
}

// ---- expansion: w -> fragment-ready bf16 Wexp image + per-pair decode ----
// item = g*256 + s*64 + q*16 + n ; pair p = g*16+n ; k0 = s*32+q*8.
// wexp[item] holds B-frag bf16x8 for (pair p, k=k0..k0+7) -> a block's 16KB
// B-tile (g = bx*4 .. bx*4+3) is CONTIGUOUS and equals the LDS image.
__global__ __launch_bounds__(256) void honu_expand(const float* __restrict__ w,
                                                   int4* __restrict__ wexp,
                                                   int2* __restrict__ dec2) {
    const int item = blockIdx.x * 256 + threadIdx.x;
    const int n = item & 15, q = (item >> 4) & 3, s = (item >> 6) & 3, g = item >> 8;
    const int p = g * 16 + n;
    int4 vout = make_int4(0, 0, 0, 0);
    if (p < NPAIR) {
        int i0, i1; dpair(p, i0, i1);
        const int mb = mbase(i0, i1);
        const int k0 = s * 32 + q * 8;
        if (k0 + 7 >= i1) {                 // run intersects band
            float f[8];
            #pragma unroll
            for (int j = 0; j < 8; ++j) {
                const int k = k0 + j;
                int off = k - i1; off = off < 0 ? 0 : off;
                const float t = w[mb + off];
                f[j] = (k >= i1) ? t : 0.0f;
            }
            vout.x = (int)bfpack2(f[0], f[1]);
            vout.y = (int)bfpack2(f[2], f[3]);
            vout.z = (int)bfpack2(f[4], f[5]);
            vout.w = (int)bfpack2(f[6], f[7]);
        }
        if ((item & 0xF0) == 0) {           // s==0 && q==0: one thread per pair
            union { float f; unsigned u; } c; c.f = w[mb + 128 - i1];
            dec2[p] = make_int2(i0 | (i1 << 16), (int)c.u);
        }
    } else if ((item & 0xF0) == 0) {
        dec2[p] = make_int2(200 << 16, 0);  // invalid sentinel: i1=200, wl=0
    }
    wexp[item] = vout;
}

// ---- main: DMA B-tile, stage x, A-frags, MFMA, fused fp32 epilogue ----
__global__ __launch_bounds__(256, 3) void honu_mfma(const float* __restrict__ x,
                                                    const int4* __restrict__ wexp,
                                                    const int2* __restrict__ dec2g,
                                                    float* __restrict__ out) {
    __shared__ float xf[64 * NF];           // 33,024 B: [row][feat], feat0 = bias
    __shared__ int4  wls[NT * NKS * 64];    // 16,384 B: linear DMA image of B-frags
    __shared__ int2  dec[64];               //    512 B: {i0|i1<<16, bits(wlast)}

    const int tid  = threadIdx.x;
    const int lane = tid & 63;
    const int wv   = tid >> 6;              // wave = 16-row M-slice
    const int bx   = blockIdx.x;            // pair chunk (64 pairs)
    const int by   = blockIdx.y;            // batch chunk (64 rows)

    // ---- async DMA: 16KB contiguous global -> linear LDS (4 issues/wave) ----
    #pragma unroll
    for (int it = 0; it < 4; ++it) {
        const int seg = it * 4 + wv;        // 16 segments x 1KB
        const int4* gp = wexp + (size_t)bx * 1024 + seg * 64 + lane;
        __builtin_amdgcn_global_load_lds(
            (const __attribute__((address_space(1))) void*)gp,
            (__attribute__((address_space(3))) void*)((char*)wls + seg * 1024),
            16, 0, 0);
    }

    // ---- stage fp32 x-tile + bias col (coalesced float4) ----
    {
        const int r = tid >> 2, q = tid & 3;
        const float4* xr = (const float4*)(x + (size_t)(by * 64 + r) * 128);
        #pragma unroll
        for (int t = 0; t < 8; ++t) {
            const int c4 = q + 4 * t;
            const float4 v = xr[c4];
            float* d = &xf[r * NF + 1 + 4 * c4];
            d[0] = v.x; d[1] = v.y; d[2] = v.z; d[3] = v.w;
        }
        if (tid < 64) xf[tid * NF] = 1.0f;
    }

    // ---- per-pair decode table: one coalesced 512B load ----
    if (tid < 64) dec[tid] = dec2g[bx * 64 + tid];
    __syncthreads();                        // drains DMA vmcnt too

    // ---- A-fragments from x-tile (this wave's 16 rows) ----
    const int am = wv * 16 + (lane & 15);
    const int aq = (lane >> 4) * 8;
    const float* xa = &xf[am * NF + aq];
    bf16x8 a[NKS];
    #pragma unroll
    for (int s = 0; s < NKS; ++s) {
        const float* p = xa + s * 32;
        i4b8 av;
        av.i.x = (int)bfpack2(p[0], p[1]);
        av.i.y = (int)bfpack2(p[2], p[3]);
        av.i.z = (int)bfpack2(p[4], p[5]);
        av.i.w = (int)bfpack2(p[6], p[7]);
        a[s] = av.b;
    }
    __syncthreads();

    // ---- MFMA loop (ds_read_b128 + MFMA) + fused fp32 epilogue ----
    const int lr0 = wv * 16 + (lane >> 4) * 4;   // local row base of C rows
    const float* r0 = &xf[lr0 * NF];
    const bf16x8* wb = (const bf16x8*)wls;
    float o0 = 0.f, o1 = 0.f, o2 = 0.f, o3 = 0.f;

    #pragma unroll
    for (int nt = 0; nt < NT; ++nt) {
        f32x4 acc = {0.f, 0.f, 0.f, 0.f};
        #pragma unroll
        for (int s = 0; s < NKS; ++s)
            acc = __builtin_amdgcn_mfma_f32_16x16x32_bf16(
                      a[s], wb[(nt * NKS + s) * 64 + lane], acc, 0, 0, 0);

        const int2 pd = dec[nt * 16 + (lane & 15)];
        const int i0 = pd.x & 0xffff;
        int i1 = pd.x >> 16; if (i1 > 128) i1 = 0;   // invalid pair: wl=0, acc=0
        union { int i; float f; } wc; wc.i = pd.y;
        const float wl = wc.f;                        // k=128 column, fp32
        o0 = fmaf(acc[0] + r0[128]          * wl, r0[i0]          * r0[i1],          o0);
        o1 = fmaf(acc[1] + r0[NF + 128]     * wl, r0[NF + i0]     * r0[NF + i1],     o1);
        o2 = fmaf(acc[2] + r0[2 * NF + 128] * wl, r0[2 * NF + i0] * r0[2 * NF + i1], o2);
        o3 = fmaf(acc[3] + r0[3 * NF + 128] * wl, r0[3 * NF + i0] * r0[3 * NF + i1], o3);
    }

    // reduce over 16 cols per quad, then one atomic per row
    #pragma unroll
    for (int msk = 1; msk < 16; msk <<= 1) {
        o0 += __shfl_xor(o0, msk);
        o1 += __shfl_xor(o1, msk);
        o2 += __shfl_xor(o2, msk);
        o3 += __shfl_xor(o3, msk);
    }
    if ((lane & 15) == 0) {
        float* po = out + by * 64 + lr0;
        atomicAdd(po + 0, o0);
        atomicAdd(po + 1, o1);
        atomicAdd(po + 2, o2);
        atomicAdd(po + 3, o3);
    }
}

extern "C" void kernel_launch(void* const* d_in, const int* in_sizes, int n_in,
                              void* d_out, int out_size, void* d_ws, size_t ws_size,
                              hipStream_t stream) {
    const float* x      = (const float*)d_in[0];
    const float* weight = (const float*)d_in[1];
    // d_in[2] (comb_idx) unused: lex order computed analytically.
    float* out  = (float*)d_out;
    int4*  wexp = (int4*)d_ws;                          // 2.06 MB fragment image
    int2*  dec2 = (int2*)((char*)d_ws + DEC_OFF);       // 67.6 KB decode table

    // Zero the 1 KiB output on-stream (graph-capture-safe): atomics accumulate.
    hipMemsetAsync(out, 0, out_size, stream);

    honu_expand<<<NGROUP, 256, 0, stream>>>(weight, wexp, dec2);
    honu_mfma<<<dim3(NCHUNK, 4), 256, 0, stream>>>(x, wexp, dec2, out);
}

// Round 4
// 69.002 us; speedup vs baseline: 1.1666x; 1.1666x over previous
//
#include <hip/hip_runtime.h>

// HONU order-3 via MFMA:
//   out[b] = sum_p xb[b,i0(p)]*xb[b,i1(p)] * S[b,p],  S = Xb @ Wexp^T,
//   Wexp[p,k] = w(i0,i1,k) for k in [i1,128], else 0 (banded, ~27% dense).
// comb_idx input ignored (lex order -> analytic weight index).
//
// R13/R14: pack hoisted to honu_expand (w -> bf16 fragment image in d_ws),
// main kernel DMAs its 16KB B-tile via global_load_lds. Result: NEUTRAL
// (79.6 -> 80.5) => pack was never the bottleneck.
// R15: the surviving shared cost is the epilogue atomic fan-in: 8448
// device-scope atomicAdds onto 256 floats (16 cache lines, 528 serialized
// RMWs/line ping-ponging across 8 non-coherent XCD L2s ~= the missing
// ~38us). Replace with disjoint partial stores part[row][bx] in d_ws
// (zero atomics) + a 64-block wave-per-row reduce kernel that WRITES out.
// Output no longer accumulated => memset node dropped as well.

#define NF      129
#define NCOMB   366145
#define NPAIR   8385            // pairs i0<=i1
#define NT      4               // 16-pair tiles per block (64 pairs)
#define NCHUNK  132             // 132*64 = 8448 >= NPAIR
#define NKS     4               // k-steps cover k=0..127; k=128 in epilogue
#define NGROUP  (NCHUNK * 4)    // 528 groups of 16 pairs
#define NPW     132             // partials per row (one per bx chunk)
#define DEC_OFF  (4u << 20)     // dec2 table at +4MB inside d_ws
#define PART_OFF (8u << 20)     // partials at +8MB inside d_ws (135KB)

typedef short bf16x8 __attribute__((ext_vector_type(8)));
typedef float f32x4  __attribute__((ext_vector_type(4)));

union i4b8 { int4 i; bf16x8 b; };

static __device__ inline unsigned bfpack2(float lo, float hi) {
    union { float f; unsigned u; } a, b; a.f = lo; b.f = hi;
    return ((b.u + 0x8000u) & 0xffff0000u) | ((a.u + 0x8000u) >> 16);
}

static __device__ inline void dpair(int p, int& i0, int& i1) {
    int t = (int)((259.0f - sqrtf((float)(67081 - 8 * p))) * 0.5f);
    t = t < 0 ? 0 : (t > 128 ? 128 : t);
    while (t < 128 && ((t + 1) * (258 - t)) / 2 <= p) ++t;
    while (t > 0   && (t * (259 - t)) / 2      >  p) --t;
    i0 = t; i1 = t + (p - (t * (259 - t)) / 2);
}

static __device__ inline int mbase(int i0, int i1) {
    const int n0 = NF - i0, n1 = NF - i1;
    return NCOMB - (n0 * (n0 + 1) * (n0 + 2)) / 6
                 + ((n0 * (n0 + 1)) >> 1) - ((n1 * (n1 + 1)) >> 1);
}

// ---- expansion: w -> fragment-ready bf16 Wexp image + per-pair decode ----
// item = g*256 + s*64 + q*16 + n ; pair p = g*16+n ; k0 = s*32+q*8.
// wexp[item] holds B-frag bf16x8 for (pair p, k=k0..k0+7) -> a block's 16KB
// B-tile (g = bx*4 .. bx*4+3) is CONTIGUOUS and equals the LDS image.
__global__ __launch_bounds__(256) void honu_expand(const float* __restrict__ w,
                                                   int4* __restrict__ wexp,
                                                   int2* __restrict__ dec2) {
    const int item = blockIdx.x * 256 + threadIdx.x;
    const int n = item & 15, q = (item >> 4) & 3, s = (item >> 6) & 3, g = item >> 8;
    const int p = g * 16 + n;
    int4 vout = make_int4(0, 0, 0, 0);
    if (p < NPAIR) {
        int i0, i1; dpair(p, i0, i1);
        const int mb = mbase(i0, i1);
        const int k0 = s * 32 + q * 8;
        if (k0 + 7 >= i1) {                 // run intersects band
            float f[8];
            #pragma unroll
            for (int j = 0; j < 8; ++j) {
                const int k = k0 + j;
                int off = k - i1; off = off < 0 ? 0 : off;
                const float t = w[mb + off];
                f[j] = (k >= i1) ? t : 0.0f;
            }
            vout.x = (int)bfpack2(f[0], f[1]);
            vout.y = (int)bfpack2(f[2], f[3]);
            vout.z = (int)bfpack2(f[4], f[5]);
            vout.w = (int)bfpack2(f[6], f[7]);
        }
        if ((item & 0xF0) == 0) {           // s==0 && q==0: one thread per pair
            union { float f; unsigned u; } c; c.f = w[mb + 128 - i1];
            dec2[p] = make_int2(i0 | (i1 << 16), (int)c.u);
        }
    } else if ((item & 0xF0) == 0) {
        dec2[p] = make_int2(200 << 16, 0);  // invalid sentinel: i1=200, wl=0
    }
    wexp[item] = vout;
}

// ---- main: DMA B-tile, stage x, A-frags, MFMA, disjoint partial stores ----
__global__ __launch_bounds__(256, 3) void honu_mfma(const float* __restrict__ x,
                                                    const int4* __restrict__ wexp,
                                                    const int2* __restrict__ dec2g,
                                                    float* __restrict__ part) {
    __shared__ float xf[64 * NF];           // 33,024 B: [row][feat], feat0 = bias
    __shared__ int4  wls[NT * NKS * 64];    // 16,384 B: linear DMA image of B-frags
    __shared__ int2  dec[64];               //    512 B: {i0|i1<<16, bits(wlast)}

    const int tid  = threadIdx.x;
    const int lane = tid & 63;
    const int wv   = tid >> 6;              // wave = 16-row M-slice
    const int bx   = blockIdx.x;            // pair chunk (64 pairs)
    const int by   = blockIdx.y;            // batch chunk (64 rows)

    // ---- async DMA: 16KB contiguous global -> linear LDS (4 issues/wave) ----
    #pragma unroll
    for (int it = 0; it < 4; ++it) {
        const int seg = it * 4 + wv;        // 16 segments x 1KB
        const int4* gp = wexp + (size_t)bx * 1024 + seg * 64 + lane;
        __builtin_amdgcn_global_load_lds(
            (const __attribute__((address_space(1))) void*)gp,
            (__attribute__((address_space(3))) void*)((char*)wls + seg * 1024),
            16, 0, 0);
    }

    // ---- stage fp32 x-tile + bias col (coalesced float4) ----
    {
        const int r = tid >> 2, q = tid & 3;
        const float4* xr = (const float4*)(x + (size_t)(by * 64 + r) * 128);
        #pragma unroll
        for (int t = 0; t < 8; ++t) {
            const int c4 = q + 4 * t;
            const float4 v = xr[c4];
            float* d = &xf[r * NF + 1 + 4 * c4];
            d[0] = v.x; d[1] = v.y; d[2] = v.z; d[3] = v.w;
        }
        if (tid < 64) xf[tid * NF] = 1.0f;
    }

    // ---- per-pair decode table: one coalesced 512B load ----
    if (tid < 64) dec[tid] = dec2g[bx * 64 + tid];
    __syncthreads();                        // drains DMA vmcnt too

    // ---- A-fragments from x-tile (this wave's 16 rows) ----
    const int am = wv * 16 + (lane & 15);
    const int aq = (lane >> 4) * 8;
    const float* xa = &xf[am * NF + aq];
    bf16x8 a[NKS];
    #pragma unroll
    for (int s = 0; s < NKS; ++s) {
        const float* p = xa + s * 32;
        i4b8 av;
        av.i.x = (int)bfpack2(p[0], p[1]);
        av.i.y = (int)bfpack2(p[2], p[3]);
        av.i.z = (int)bfpack2(p[4], p[5]);
        av.i.w = (int)bfpack2(p[6], p[7]);
        a[s] = av.b;
    }
    __syncthreads();

    // ---- MFMA loop (ds_read_b128 + MFMA) + fused fp32 epilogue ----
    const int lr0 = wv * 16 + (lane >> 4) * 4;   // local row base of C rows
    const float* r0 = &xf[lr0 * NF];
    const bf16x8* wb = (const bf16x8*)wls;
    float o0 = 0.f, o1 = 0.f, o2 = 0.f, o3 = 0.f;

    #pragma unroll
    for (int nt = 0; nt < NT; ++nt) {
        f32x4 acc = {0.f, 0.f, 0.f, 0.f};
        #pragma unroll
        for (int s = 0; s < NKS; ++s)
            acc = __builtin_amdgcn_mfma_f32_16x16x32_bf16(
                      a[s], wb[(nt * NKS + s) * 64 + lane], acc, 0, 0, 0);

        const int2 pd = dec[nt * 16 + (lane & 15)];
        const int i0 = pd.x & 0xffff;
        int i1 = pd.x >> 16; if (i1 > 128) i1 = 0;   // invalid pair: wl=0, acc=0
        union { int i; float f; } wc; wc.i = pd.y;
        const float wl = wc.f;                        // k=128 column, fp32
        o0 = fmaf(acc[0] + r0[128]          * wl, r0[i0]          * r0[i1],          o0);
        o1 = fmaf(acc[1] + r0[NF + 128]     * wl, r0[NF + i0]     * r0[NF + i1],     o1);
        o2 = fmaf(acc[2] + r0[2 * NF + 128] * wl, r0[2 * NF + i0] * r0[2 * NF + i1], o2);
        o3 = fmaf(acc[3] + r0[3 * NF + 128] * wl, r0[3 * NF + i0] * r0[3 * NF + i1], o3);
    }

    // reduce over 16 cols per quad, then ONE disjoint store per row (no atomics)
    #pragma unroll
    for (int msk = 1; msk < 16; msk <<= 1) {
        o0 += __shfl_xor(o0, msk);
        o1 += __shfl_xor(o1, msk);
        o2 += __shfl_xor(o2, msk);
        o3 += __shfl_xor(o3, msk);
    }
    if ((lane & 15) == 0) {
        float* pp = part + (size_t)(by * 64 + lr0) * NPW + bx;
        pp[0]       = o0;
        pp[NPW]     = o1;
        pp[2 * NPW] = o2;
        pp[3 * NPW] = o3;
    }
}

// ---- final reduce: one wave per output row, coalesced, writes out ----
__global__ __launch_bounds__(256) void honu_reduce(const float* __restrict__ part,
                                                   float* __restrict__ out) {
    const int lane = threadIdx.x & 63;
    const int r = blockIdx.x * 4 + (threadIdx.x >> 6);
    const float* pr = part + (size_t)r * NPW;
    float s = pr[lane] + pr[64 + lane] + (lane < 4 ? pr[128 + lane] : 0.f);
    #pragma unroll
    for (int m = 32; m >= 1; m >>= 1) s += __shfl_xor(s, m);
    if (lane == 0) out[r] = s;
}

extern "C" void kernel_launch(void* const* d_in, const int* in_sizes, int n_in,
                              void* d_out, int out_size, void* d_ws, size_t ws_size,
                              hipStream_t stream) {
    const float* x      = (const float*)d_in[0];
    const float* weight = (const float*)d_in[1];
    // d_in[2] (comb_idx) unused: lex order computed analytically.
    float* out  = (float*)d_out;
    int4*  wexp = (int4*)d_ws;                          // 2.06 MB fragment image
    int2*  dec2 = (int2*)((char*)d_ws + DEC_OFF);       // 67.6 KB decode table
    float* part = (float*)((char*)d_ws + PART_OFF);     // 135 KB partials [row][bx]

    honu_expand<<<NGROUP, 256, 0, stream>>>(weight, wexp, dec2);
    honu_mfma<<<dim3(NCHUNK, 4), 256, 0, stream>>>(x, wexp, dec2, part);
    honu_reduce<<<64, 256, 0, stream>>>(part, out);
}

// Round 5
// 68.418 us; speedup vs baseline: 1.1765x; 1.0085x over previous
//
#include <hip/hip_runtime.h>

// HONU order-3 via MFMA:
//   out[b] = sum_p xb[b,i0(p)]*xb[b,i1(p)] * S[b,p],  S = Xb @ Wexp^T,
//   Wexp[p,k] = w(i0,i1,k) for k in [i1,128], else 0 (banded, ~27% dense).
// comb_idx input ignored (lex order -> analytic weight index).
//
// R15: atomic fan-in removed (8448 device-scope RMWs on 16 lines) -> 80.5->69.0.
// R16: collapse the 3-node pipeline. The workload is L2-resident and
// latency-bound (~28us pipeline vs 0.23us of MFMA math): expand kernel +
// 2MB image round-trip + 4x by-duplication + 2 dependency drains were pure
// overhead. Now ONE 1024-thread block per bx chunk covers the whole batch
// (M=256) in LDS: stage x once (129KB), decode+pack B-tile once in-LDS
// (16KB, values bit-identical to R12/R15), 16 waves x 16 MFMAs, fp32
// epilogue, disjoint partial stores; then the unchanged wave-per-row reduce.
// 2 kernels, no atomics, no global fragment image.

#define NF      129
#define NCOMB   366145
#define NPAIR   8385            // pairs i0<=i1
#define NT      4               // 16-pair tiles per block (64 pairs)
#define NCHUNK  132             // 132*64 = 8448 >= NPAIR
#define NKS     4               // k-steps cover k=0..127; k=128 in epilogue
#define NPW     132             // partials per row (one per bx chunk)

typedef short bf16x8 __attribute__((ext_vector_type(8)));
typedef float f32x4  __attribute__((ext_vector_type(4)));

union i4b8 { int4 i; bf16x8 b; };

static __device__ inline unsigned bfpack2(float lo, float hi) {
    union { float f; unsigned u; } a, b; a.f = lo; b.f = hi;
    return ((b.u + 0x8000u) & 0xffff0000u) | ((a.u + 0x8000u) >> 16);
}

static __device__ inline void dpair(int p, int& i0, int& i1) {
    int t = (int)((259.0f - sqrtf((float)(67081 - 8 * p))) * 0.5f);
    t = t < 0 ? 0 : (t > 128 ? 128 : t);
    while (t < 128 && ((t + 1) * (258 - t)) / 2 <= p) ++t;
    while (t > 0   && (t * (259 - t)) / 2      >  p) --t;
    i0 = t; i1 = t + (p - (t * (259 - t)) / 2);
}

static __device__ inline int mbase(int i0, int i1) {
    const int n0 = NF - i0, n1 = NF - i1;
    return NCOMB - (n0 * (n0 + 1) * (n0 + 2)) / 6
                 + ((n0 * (n0 + 1)) >> 1) - ((n1 * (n1 + 1)) >> 1);
}

// ---- fused: one block per 64-pair chunk, full 256-row batch in LDS ----
__global__ __launch_bounds__(1024, 1) void honu_fused2(const float* __restrict__ x,
                                                       const float* __restrict__ w,
                                                       float* __restrict__ part) {
    __shared__ float  xf[256 * NF];         // 132,096 B: [row][feat], feat0 = bias
    __shared__ bf16x8 wls[NT * NKS * 64];   //  16,384 B: B-frags [(nt*4+s)*64+lane]
    __shared__ int2   dec[64];              //     512 B: {i0|i1<<16, bits(wlast)}

    const int tid  = threadIdx.x;
    const int lane = tid & 63;
    const int wv   = tid >> 6;              // 16 waves: wave = 16-row M-slice
    const int bx   = blockIdx.x;            // pair chunk (64 pairs)

    // ---- stage fp32 x-tile (all 256 rows) + bias col (coalesced float4) ----
    {
        const int r = tid >> 2, q = tid & 3;
        const float4* xr = (const float4*)(x + (size_t)r * 128);
        #pragma unroll
        for (int t = 0; t < 8; ++t) {
            const int c4 = q + 4 * t;
            const float4 v = xr[c4];
            float* d = &xf[r * NF + 1 + 4 * c4];
            d[0] = v.x; d[1] = v.y; d[2] = v.z; d[3] = v.w;
        }
        if (tid < 256) xf[tid * NF] = 1.0f;
    }

    // ---- decode this block's 64 pairs (+ wlast = w at k=128) ----
    if (tid < 64) {
        const int p = bx * 64 + tid;
        int i0 = 0, i1 = 200; unsigned wl = 0;       // i1=200: invalid sentinel
        if (p < NPAIR) {
            int mb; dpair(p, i0, i1);
            mb = mbase(i0, i1);
            union { float f; unsigned u; } c; c.f = w[mb + 128 - i1];
            wl = c.u;
        }
        dec[tid] = make_int2(i0 | (i1 << 16), (int)wl);
    }
    __syncthreads();

    // ---- pack B-fragments once: item = pair*16 + run (k = run*8..+7) ----
    {
        const int pl = tid >> 4, r = tid & 15;       // 1024 items, 1/thread
        const int2 pd = dec[pl];
        const int i1 = pd.x >> 16;
        const int k0 = r * 8;
        int4 vout = make_int4(0, 0, 0, 0);
        if (k0 + 7 >= i1) {                          // intersects band (invalid: false)
            const int p = bx * 64 + pl;
            int a0, a1; dpair(p, a0, a1);
            const int mb = mbase(a0, a1);
            float f[8];
            #pragma unroll
            for (int j = 0; j < 8; ++j) {
                const int k = k0 + j;
                int off = k - i1; off = off < 0 ? 0 : off;
                const float t = w[mb + off];         // per-16-thread-group contiguous
                f[j] = (k >= i1) ? t : 0.0f;
            }
            vout.x = (int)bfpack2(f[0], f[1]);
            vout.y = (int)bfpack2(f[2], f[3]);
            vout.z = (int)bfpack2(f[4], f[5]);
            vout.w = (int)bfpack2(f[6], f[7]);
        }
        const int nt = pl >> 4, s = r >> 2;
        const int slane = ((r & 3) << 4) | (pl & 15);
        ((int4*)wls)[(nt * NKS + s) * 64 + slane] = vout;   // ds_write_b128
    }

    // ---- A-fragments from x-tile (this wave's 16 rows; k<=127) ----
    const int am = wv * 16 + (lane & 15);
    const int aq = (lane >> 4) * 8;
    const float* xa = &xf[am * NF + aq];
    bf16x8 a[NKS];
    #pragma unroll
    for (int s = 0; s < NKS; ++s) {
        const float* p = xa + s * 32;
        i4b8 av;
        av.i.x = (int)bfpack2(p[0], p[1]);
        av.i.y = (int)bfpack2(p[2], p[3]);
        av.i.z = (int)bfpack2(p[4], p[5]);
        av.i.w = (int)bfpack2(p[6], p[7]);
        a[s] = av.b;
    }
    __syncthreads();

    // ---- MFMA loop (ds_read_b128 + MFMA) + fused fp32 epilogue ----
    const int lr0 = wv * 16 + (lane >> 4) * 4;   // row base of C rows (0..255)
    const float* r0 = &xf[lr0 * NF];
    float o0 = 0.f, o1 = 0.f, o2 = 0.f, o3 = 0.f;

    #pragma unroll
    for (int nt = 0; nt < NT; ++nt) {
        f32x4 acc = {0.f, 0.f, 0.f, 0.f};
        #pragma unroll
        for (int s = 0; s < NKS; ++s)
            acc = __builtin_amdgcn_mfma_f32_16x16x32_bf16(
                      a[s], wls[(nt * NKS + s) * 64 + lane], acc, 0, 0, 0);

        const int2 pd = dec[nt * 16 + (lane & 15)];
        const int i0 = pd.x & 0xffff;
        int i1 = pd.x >> 16; if (i1 > 128) i1 = 0;   // invalid pair: wl=0, acc=0
        union { int i; float f; } wc; wc.i = pd.y;
        const float wl = wc.f;                        // k=128 column, fp32
        o0 = fmaf(acc[0] + r0[128]          * wl, r0[i0]          * r0[i1],          o0);
        o1 = fmaf(acc[1] + r0[NF + 128]     * wl, r0[NF + i0]     * r0[NF + i1],     o1);
        o2 = fmaf(acc[2] + r0[2 * NF + 128] * wl, r0[2 * NF + i0] * r0[2 * NF + i1], o2);
        o3 = fmaf(acc[3] + r0[3 * NF + 128] * wl, r0[3 * NF + i0] * r0[3 * NF + i1], o3);
    }

    // reduce over 16 cols per quad, then ONE disjoint store per row (no atomics)
    #pragma unroll
    for (int msk = 1; msk < 16; msk <<= 1) {
        o0 += __shfl_xor(o0, msk);
        o1 += __shfl_xor(o1, msk);
        o2 += __shfl_xor(o2, msk);
        o3 += __shfl_xor(o3, msk);
    }
    if ((lane & 15) == 0) {
        float* pp = part + (size_t)lr0 * NPW + bx;
        pp[0]       = o0;
        pp[NPW]     = o1;
        pp[2 * NPW] = o2;
        pp[3 * NPW] = o3;
    }
}

// ---- final reduce: one wave per output row, coalesced, writes out ----
__global__ __launch_bounds__(256) void honu_reduce(const float* __restrict__ part,
                                                   float* __restrict__ out) {
    const int lane = threadIdx.x & 63;
    const int r = blockIdx.x * 4 + (threadIdx.x >> 6);
    const float* pr = part + (size_t)r * NPW;
    float s = pr[lane] + pr[64 + lane] + (lane < 4 ? pr[128 + lane] : 0.f);
    #pragma unroll
    for (int m = 32; m >= 1; m >>= 1) s += __shfl_xor(s, m);
    if (lane == 0) out[r] = s;
}

extern "C" void kernel_launch(void* const* d_in, const int* in_sizes, int n_in,
                              void* d_out, int out_size, void* d_ws, size_t ws_size,
                              hipStream_t stream) {
    const float* x      = (const float*)d_in[0];
    const float* weight = (const float*)d_in[1];
    // d_in[2] (comb_idx) unused: lex order computed analytically.
    float* out  = (float*)d_out;
    float* part = (float*)d_ws;             // 135 KB partials [row][bx]

    honu_fused2<<<NCHUNK, 1024, 0, stream>>>(x, weight, part);
    honu_reduce<<<64, 256, 0, stream>>>(part, out);
}